// Round 6
// baseline (20.131 us; speedup 1.0000x reference)
//
#include <hip/hip_runtime.h>

#define TT 2048
#define BB 512

#if __has_builtin(__builtin_amdgcn_exp2f)
__device__ __forceinline__ float fexp2(float x){ return __builtin_amdgcn_exp2f(x); }
#else
__device__ __forceinline__ float fexp2(float x){ return exp2f(x); }
#endif
#if __has_builtin(__builtin_amdgcn_logf)
__device__ __forceinline__ float flog2(float x){ return __builtin_amdgcn_logf(x); }
#else
__device__ __forceinline__ float flog2(float x){ return log2f(x); }
#endif
__device__ __forceinline__ float frcp(float x){ return __builtin_amdgcn_rcpf(x); }

// ---- fp8 e4m3 pack/unpack (OCP, gfx950 HW cvt) ----
#if __has_builtin(__builtin_amdgcn_cvt_pk_fp8_f32) && __has_builtin(__builtin_amdgcn_cvt_pk_f32_fp8)
__device__ __forceinline__ unsigned enc_lo(float a,float b,unsigned old){
  return (unsigned)__builtin_amdgcn_cvt_pk_fp8_f32(a,b,(int)old,false);
}
__device__ __forceinline__ unsigned enc_hi(float a,float b,unsigned old){
  return (unsigned)__builtin_amdgcn_cvt_pk_fp8_f32(a,b,(int)old,true);
}
__device__ __forceinline__ void dec_lo(unsigned w,float&x,float&y){
  auto r=__builtin_amdgcn_cvt_pk_f32_fp8((int)w,false); x=r[0]; y=r[1];
}
__device__ __forceinline__ void dec_hi(unsigned w,float&x,float&y){
  auto r=__builtin_amdgcn_cvt_pk_f32_fp8((int)w,true); x=r[0]; y=r[1];
}
#else
__device__ __forceinline__ unsigned enc1(float x){
  if (!(x > 0x1p-10f)) return 0u;
  unsigned b = __float_as_uint(x) + 0x80000u;     // round mantissa to 3 bits
  int e = (int)((b>>23)&0xFF) - 127;
  if (e < -6){ int m = (int)(x*512.0f + 0.5f); return (unsigned)m; }
  if (e > 8) return 0x7Eu;
  return (unsigned)(((e+7)<<3) | ((b>>20)&7));
}
__device__ __forceinline__ float dec1(unsigned byte){
  unsigned e=(byte>>3)&0xF, m=byte&7;
  if (e==0) return (float)m * 0x1p-9f;
  return __uint_as_float(((e+120u)<<23)|(m<<20));
}
__device__ __forceinline__ unsigned enc_lo(float a,float b,unsigned old){
  return (old & 0xFFFF0000u) | enc1(a) | (enc1(b)<<8);
}
__device__ __forceinline__ unsigned enc_hi(float a,float b,unsigned old){
  return (old & 0x0000FFFFu) | (enc1(a)<<16) | (enc1(b)<<24);
}
__device__ __forceinline__ void dec_lo(unsigned w,float&x,float&y){ x=dec1(w&0xFF); y=dec1((w>>8)&0xFF); }
__device__ __forceinline__ void dec_hi(unsigned w,float&x,float&y){ x=dec1((w>>16)&0xFF); y=dec1(w>>24); }
#endif

__device__ __forceinline__ float lse2_4(float x0,float x1,float x2,float x3){
  float m = fmaxf(fmaxf(x0,x1),fmaxf(x2,x3));
  float e = fexp2(x0-m)+fexp2(x1-m)+fexp2(x2-m)+fexp2(x3-m);
  return m + flog2(e);
}

__global__ __launch_bounds__(512, 4) void crf_kernel(
    const float* __restrict__ trans,      // [6,6]
    const float* __restrict__ w,          // [4]
    const float* __restrict__ mult,       // [4,4]
    const float* __restrict__ out_table,  // [V,4]
    const float* __restrict__ bias,       // [B,T]
    const int*   __restrict__ sentence,   // [B,T]
    const int*   __restrict__ tags,       // [B,T]
    float* __restrict__ out)              // [B]
{
  constexpr float INVLN2 = 1.4426950408889634f;
  constexpr float LN2    = 0.6931471805599453f;
  const int b   = blockIdx.x;
  const int tid = threadIdx.x;

  // Te fp8: one 16B granule per t, swizzled granule = t ^ ((t>>5)&7)
  __shared__ __align__(16) char  s_te[32768];
  __shared__ __align__(16) float s_c[2048];      // per-t log2 normalizers
  __shared__ float s_PAm[128*16];
  __shared__ float s_PAs[128*4];
  __shared__ float s_M[16];
  __shared__ float s_tr[36];
  __shared__ float s_wgold[8];
  float* s_PBm = (float*)s_te;                    // aliased after scan reads done
  float* s_PBs = (float*)(s_te + 16384);

  // ---- per-thread constants ----
  float trans2[16]; float t2max = -1e30f;
  #pragma unroll
  for (int i=0;i<4;i++)
    #pragma unroll
    for (int k=0;k<4;k++){
      float v = trans[i*6+k]*INVLN2;
      trans2[i*4+k] = v; t2max = fmaxf(t2max, v);
    }
  const float T144 = t2max + 1.4427f;

  float M[16];
  {
    float e[16]; float cs[4]={0.f,0.f,0.f,0.f};
    #pragma unroll
    for (int i=0;i<4;i++)
      #pragma unroll
      for (int j=0;j<4;j++){
        float v = fexp2(mult[i*4+j]*INVLN2);
        e[i*4+j]=v; cs[j]+=v;
      }
    #pragma unroll
    for (int j=0;j<4;j++) cs[j]=frcp(cs[j]);
    #pragma unroll
    for (int i=0;i<4;i++)
      #pragma unroll
      for (int j=0;j<4;j++)
        M[i*4+j] = (i==j) ? -1.f : e[i*4+j]*cs[j];
  }
  const float wc0=w[0]*2.f*INVLN2, wc1=w[1]*2.f*INVLN2,
              wc2=w[2]*2.f*INVLN2, wc3=w[3]*2.f*INVLN2;
  if (tid<36) s_tr[tid]=trans[tid];
  if (tid==0){
    #pragma unroll
    for (int i=0;i<16;i++) s_M[i]=M[i];
  }
  __syncthreads();

  // ---- phase 0: 4 consecutive t per thread; vector loads; fp8 Te + gold ----
  float gold = 0.f;
  {
    const int t0   = tid<<2;
    const int base = b*TT + t0;
    float4 bb4 = *reinterpret_cast<const float4*>(bias + base);
    int4  sen4 = *reinterpret_cast<const int4*>(sentence + base);
    int4  tg4  = *reinterpret_cast<const int4*>(tags + base);
    float4 ft0 = *reinterpret_cast<const float4*>(out_table + (size_t)sen4.x*4);
    float4 ft1 = *reinterpret_cast<const float4*>(out_table + (size_t)sen4.y*4);
    float4 ft2 = *reinterpret_cast<const float4*>(out_table + (size_t)sen4.z*4);
    float4 ft3 = *reinterpret_cast<const float4*>(out_table + (size_t)sen4.w*4);

    int pv0 = __shfl_up(tg4.w, 1);
    if ((tid & 63)==0 && t0>0) pv0 = tags[base-1];

    float cv[4];
    #pragma unroll
    for (int e=0;e<4;e++){
      const int t = t0 + e;
      float bb   = (e==0)?bb4.x:(e==1)?bb4.y:(e==2)?bb4.z:bb4.w;
      float4 f4e = (e==0)?ft0:(e==1)?ft1:(e==2)?ft2:ft3;
      int tg     = (e==0)?tg4.x:(e==1)?tg4.y:(e==2)?tg4.z:tg4.w;

      // shift_k = bb*tanh((bb-0.5)*w_k) via exp2+rcp
      float bh = bb-0.5f;
      float y0=fexp2(bh*wc0); float sh0=bb*(y0-1.f)*frcp(y0+1.f);
      float y1=fexp2(bh*wc1); float sh1=bb*(y1-1.f)*frcp(y1+1.f);
      float y2=fexp2(bh*wc2); float sh2v=bb*(y2-1.f)*frcp(y2+1.f);
      float y3=fexp2(bh*wc3); float sh3=bb*(y3-1.f)*frcp(y3+1.f);
      float s20=sh0*INVLN2, s21=sh1*INVLN2, s22=sh2v*INVLN2, s23=sh3*INVLN2;
      float f20=f4e.x*INVLN2, f21=f4e.y*INVLN2, f22=f4e.z*INVLN2, f23=f4e.w*INVLN2;

      // uniform normalizer: all args <= ct; stored = exp2(arg - ct + 8) in (0,256]
      float ct  = fmaxf(fmaxf(f20,f21),fmaxf(f22,f23)) + T144;
      float off = 8.0f - ct;
      float o0=f20+off, o1=f21+off, o2=f22+off, o3=f23+off;
      float a00=fexp2(fmaf(M[ 0],s20,trans2[ 0]+o0));
      float a01=fexp2(fmaf(M[ 1],s21,trans2[ 1]+o0));
      float a02=fexp2(fmaf(M[ 2],s22,trans2[ 2]+o0));
      float a03=fexp2(fmaf(M[ 3],s23,trans2[ 3]+o0));
      float a10=fexp2(fmaf(M[ 4],s20,trans2[ 4]+o1));
      float a11=fexp2(fmaf(M[ 5],s21,trans2[ 5]+o1));
      float a12=fexp2(fmaf(M[ 6],s22,trans2[ 6]+o1));
      float a13=fexp2(fmaf(M[ 7],s23,trans2[ 7]+o1));
      float a20=fexp2(fmaf(M[ 8],s20,trans2[ 8]+o2));
      float a21=fexp2(fmaf(M[ 9],s21,trans2[ 9]+o2));
      float a22=fexp2(fmaf(M[10],s22,trans2[10]+o2));
      float a23=fexp2(fmaf(M[11],s23,trans2[11]+o2));
      float a30=fexp2(fmaf(M[12],s20,trans2[12]+o3));
      float a31=fexp2(fmaf(M[13],s21,trans2[13]+o3));
      float a32=fexp2(fmaf(M[14],s22,trans2[14]+o3));
      float a33=fexp2(fmaf(M[15],s23,trans2[15]+o3));

      unsigned d0=enc_lo(a00,a01,0u); d0=enc_hi(a02,a03,d0);
      unsigned d1=enc_lo(a10,a11,0u); d1=enc_hi(a12,a13,d1);
      unsigned d2=enc_lo(a20,a21,0u); d2=enc_hi(a22,a23,d2);
      unsigned d3=enc_lo(a30,a31,0u); d3=enc_hi(a32,a33,d3);
      int K=(t>>5)&7; int g=(t^K)<<4;
      *reinterpret_cast<uint4*>(s_te+g) = make_uint4(d0,d1,d2,d3);
      cv[e]=ct;

      // gold
      int pv = (e==0)?pv0:((e==1)?tg4.x:(e==2)?tg4.y:tg4.z);
      float term;
      if (t==0){
        term = s_tr[tg*6+4];
      } else {
        float shp=(pv==0)?sh0:(pv==1)?sh1:(pv==2)?sh2v:sh3;
        term = s_tr[tg*6+pv] + shp*s_M[tg*4+pv];
      }
      term += (tg==0)?f4e.x:(tg==1)?f4e.y:(tg==2)?f4e.z:f4e.w;
      if (t==TT-1) term += s_tr[30+tg];
      gold += term;
    }
    *reinterpret_cast<float4*>(reinterpret_cast<char*>(s_c)+(t0<<2)) =
        make_float4(cv[0],cv[1],cv[2],cv[3]);
    if (tid==0){   // plant identity at t=0 (chunk 0 then needs no branch)
      *reinterpret_cast<uint4*>(s_te) = make_uint4(0x38u,0x3800u,0x380000u,0x38000000u);
      s_c[0] = 8.0f;
    }
  }
  #pragma unroll
  for (int off=32; off>0; off>>=1) gold += __shfl_down(gold, off);
  if ((tid & 63)==0) s_wgold[tid>>6] = gold;
  __syncthreads();

  // ---- phase 1: 128 chunks x 16 steps; fp8 matvec, 1 ds_read_b128/step ----
  {
    int c = tid>>2, j = tid&3;
    int t0c = c<<4;
    int K  = (t0c>>5)&7;
    float p0=(j==0)?1.f:0.f, p1=(j==1)?1.f:0.f, p2=(j==2)?1.f:0.f, p3=(j==3)?1.f:0.f;
    float L = 0.f;
    #pragma unroll
    for (int s=0;s<16;s++){
      int g = ((t0c+s) ^ K) << 4;
      uint4 q = *reinterpret_cast<const uint4*>(s_te + g);
      float e0,e1,e2,e3;
      dec_lo(q.x,e0,e1); dec_hi(q.x,e2,e3);
      float n0 = fmaf(e0,p0, e1*p1); n0 = fmaf(e2,p2,n0); n0 = fmaf(e3,p3,n0);
      dec_lo(q.y,e0,e1); dec_hi(q.y,e2,e3);
      float n1 = fmaf(e0,p0, e1*p1); n1 = fmaf(e2,p2,n1); n1 = fmaf(e3,p3,n1);
      dec_lo(q.z,e0,e1); dec_hi(q.z,e2,e3);
      float n2 = fmaf(e0,p0, e1*p1); n2 = fmaf(e2,p2,n2); n2 = fmaf(e3,p3,n2);
      dec_lo(q.w,e0,e1); dec_hi(q.w,e2,e3);
      float n3 = fmaf(e0,p0, e1*p1); n3 = fmaf(e2,p2,n3); n3 = fmaf(e3,p3,n3);
      p0=n0; p1=n1; p2=n2; p3=n3;
      if ((s&7)==7){
        float sum = fmaxf((p0+p1)+(p2+p3), 1e-30f);
        float inv = frcp(sum);
        L += flog2(sum);
        p0*=inv; p1*=inv; p2*=inv; p3*=inv;
      }
    }
    // add per-t normalizer corrections: sum(c_t) - 16*8
    const float4* cp = reinterpret_cast<const float4*>(
        reinterpret_cast<const char*>(s_c)+(t0c<<2));
    float4 ca=cp[0], cb=cp[1], cc=cp[2], cd=cp[3];
    L += ((ca.x+ca.y+ca.z+ca.w)+(cb.x+cb.y+cb.z+cb.w))
       + ((cc.x+cc.y+cc.z+cc.w)+(cd.x+cd.y+cd.z+cd.w)) - 128.0f;

    s_PAm[c*16 + 0*4 + j] = p0;
    s_PAm[c*16 + 1*4 + j] = p1;
    s_PAm[c*16 + 2*4 + j] = p2;
    s_PAm[c*16 + 3*4 + j] = p3;
    s_PAs[c*4 + j] = L;
  }
  __syncthreads();   // all s_te/s_c reads done before PB alias writes

  // ---- phase 2: tree combine (prob domain with per-column scales), 7 levels ----
  float *srcM = s_PAm, *srcS = s_PAs, *dstM = s_PBm, *dstS = s_PBs;
  #pragma unroll 1
  for (int n=64; n>=1; n>>=1){
    if (tid < n*4){
      int p = tid>>2, j = tid&3;
      const float* Am = srcM + (2*p)*16;
      const float* As = srcS + (2*p)*4;
      const float* Bm = Am + 16;
      const float* Bs = As + 4;
      float b0=Bs[0], b1=Bs[1], b2=Bs[2], b3=Bs[3];
      float m = fmaxf(fmaxf(b0,b1), fmaxf(b2,b3));
      float a0 = Am[0*4+j]*fexp2(b0-m);
      float a1 = Am[1*4+j]*fexp2(b1-m);
      float a2 = Am[2*4+j]*fexp2(b2-m);
      float a3 = Am[3*4+j]*fexp2(b3-m);
      float c0 = fmaf(Bm[ 0],a0, fmaf(Bm[ 1],a1, fmaf(Bm[ 2],a2, Bm[ 3]*a3)));
      float c1 = fmaf(Bm[ 4],a0, fmaf(Bm[ 5],a1, fmaf(Bm[ 6],a2, Bm[ 7]*a3)));
      float c2 = fmaf(Bm[ 8],a0, fmaf(Bm[ 9],a1, fmaf(Bm[10],a2, Bm[11]*a3)));
      float c3 = fmaf(Bm[12],a0, fmaf(Bm[13],a1, fmaf(Bm[14],a2, Bm[15]*a3)));
      float ssum = fmaxf((c0+c1)+(c2+c3), 1e-37f);
      float inv = frcp(ssum);
      dstM[p*16+0*4+j] = c0*inv;
      dstM[p*16+1*4+j] = c1*inv;
      dstM[p*16+2*4+j] = c2*inv;
      dstM[p*16+3*4+j] = c3*inv;
      dstS[p*4+j] = m + As[j] + flog2(ssum);
    }
    __syncthreads();
    float* tm;
    tm=srcM; srcM=dstM; dstM=tm;
    tm=srcS; srcS=dstS; dstS=tm;
  }

  // ---- final ----
  if (tid==0){
    const float* Pf = srcM;
    const float* Ls = srcS;
    int s0 = sentence[b*TT];
    float4 f0 = *reinterpret_cast<const float4*>(out_table + (size_t)s0*4);
    float a0 = (trans[ 4] + f0.x)*INVLN2;
    float a1 = (trans[10] + f0.y)*INVLN2;
    float a2 = (trans[16] + f0.z)*INVLN2;
    float a3 = (trans[22] + f0.w)*INVLN2;
    float u0 = Ls[0]+a0, u1 = Ls[1]+a1, u2 = Ls[2]+a2, u3 = Ls[3]+a3;
    float m2 = fmaxf(fmaxf(u0,u1), fmaxf(u2,u3));
    float e0 = fexp2(u0-m2), e1 = fexp2(u1-m2), e2 = fexp2(u2-m2), e3 = fexp2(u3-m2);
    float v0 = fmaf(Pf[ 0],e0, fmaf(Pf[ 1],e1, fmaf(Pf[ 2],e2, Pf[ 3]*e3)));
    float v1 = fmaf(Pf[ 4],e0, fmaf(Pf[ 5],e1, fmaf(Pf[ 6],e2, Pf[ 7]*e3)));
    float v2 = fmaf(Pf[ 8],e0, fmaf(Pf[ 9],e1, fmaf(Pf[10],e2, Pf[11]*e3)));
    float v3 = fmaf(Pf[12],e0, fmaf(Pf[13],e1, fmaf(Pf[14],e2, Pf[15]*e3)));
    float n0 = flog2(v0)+m2, n1 = flog2(v1)+m2, n2 = flog2(v2)+m2, n3 = flog2(v3)+m2;
    float fwd2 = lse2_4(n0+trans[30]*INVLN2, n1+trans[31]*INVLN2,
                        n2+trans[32]*INVLN2, n3+trans[33]*INVLN2);
    float g = ((s_wgold[0]+s_wgold[1])+(s_wgold[2]+s_wgold[3]))
            + ((s_wgold[4]+s_wgold[5])+(s_wgold[6]+s_wgold[7]));
    out[b] = fwd2*LN2 - g;
  }
}

extern "C" void kernel_launch(void* const* d_in, const int* in_sizes, int n_in,
                              void* d_out, int out_size, void* d_ws, size_t ws_size,
                              hipStream_t stream) {
  const float* trans     = (const float*)d_in[0];
  const float* w         = (const float*)d_in[1];
  const float* mult      = (const float*)d_in[2];
  const float* out_table = (const float*)d_in[3];
  const float* bias      = (const float*)d_in[4];
  const int*   sentence  = (const int*)d_in[5];
  const int*   tags      = (const int*)d_in[6];
  crf_kernel<<<BB, 512, 0, stream>>>(trans, w, mult, out_table, bias, sentence, tags,
                                     (float*)d_out);
}